// Round 5
// baseline (400.421 us; speedup 1.0000x reference)
//
#include <hip/hip_runtime.h>
#include <stdint.h>

typedef int v4i  __attribute__((ext_vector_type(4)));
typedef int v16i __attribute__((ext_vector_type(16)));

static constexpr int MDIM = 8192;   // B * S
static constexpr int NDIM = 4096;   // D_OUT
static constexpr int KDIM = 4096;   // D_IN

static constexpr int QBLOCKS = (MDIM * KDIM / 16) / 256;  // 8192
static constexpr int WBLOCKS = (NDIM * KDIM / 16) / 256;  // 4096

// Async global->LDS, 16B per lane: HW writes lane i at (wave-uniform base) + i*16.
__device__ __forceinline__ void lds_load16(const void* gptr, void* lptr) {
    __builtin_amdgcn_global_load_lds(
        (const __attribute__((address_space(1))) void*)(uintptr_t)gptr,
        (__attribute__((address_space(3))) void*)(uint32_t)(uintptr_t)lptr,
        16, 0, 0);
}

__device__ __forceinline__ int q1(float f, float s) {
    return (int)fminf(fmaxf(__builtin_rintf(f / s), -128.0f), 127.0f);
}
__device__ __forceinline__ int pack4(int a, int b, int c, int d) {
    return (a & 0xff) | ((b & 0xff) << 8) | ((c & 0xff) << 16) | ((d & 0xff) << 24);
}

__global__ __launch_bounds__(256) void prep_k(const float4* __restrict__ x,
                                              int4* __restrict__ xq,
                                              const int4* __restrict__ w,
                                              int4* __restrict__ wq,
                                              const float* __restrict__ s_in) {
    const int b = blockIdx.x;
    if (b < QBLOCKS) {
        const int i = b * 256 + threadIdx.x;
        const float s = s_in[0];
        const float4 v0 = x[4 * i + 0];
        const float4 v1 = x[4 * i + 1];
        const float4 v2 = x[4 * i + 2];
        const float4 v3 = x[4 * i + 3];
        int4 o;
        o.x = pack4(q1(v0.x, s), q1(v0.y, s), q1(v0.z, s), q1(v0.w, s));
        o.y = pack4(q1(v1.x, s), q1(v1.y, s), q1(v1.z, s), q1(v1.w, s));
        o.z = pack4(q1(v2.x, s), q1(v2.y, s), q1(v2.z, s), q1(v2.w, s));
        o.w = pack4(q1(v3.x, s), q1(v3.y, s), q1(v3.z, s), q1(v3.w, s));
        xq[i] = o;
    } else {
        const int i = (b - QBLOCKS) * 256 + threadIdx.x;
        const int4 a = w[4 * i + 0];
        const int4 c = w[4 * i + 1];
        const int4 d = w[4 * i + 2];
        const int4 e = w[4 * i + 3];
        int4 o;
        o.x = pack4(a.x, a.y, a.z, a.w);
        o.y = pack4(c.x, c.y, c.z, c.w);
        o.z = pack4(d.x, d.y, d.z, d.w);
        o.w = pack4(e.x, e.y, e.z, e.w);
        wq[i] = o;
    }
}

// ============================================================================
// 256x256 tile, FAT 4-phase K-loop (2 K-tiles / 4 phases), 32x32x32 i8 MFMA.
// LDS layout / swizzle / staging geometry byte-identical to the verified
// 0-conflict kernels. One phase = one (slot, K-half) region, full 128x64
// wave output: 16 MFMA/wave (4 mtiles x 2 ntiles x 2 ksteps) = 1171 MFMA
// cyc/SIMD per phase -- amortizes the measured ~590-cyc phase-skeleton
// overhead over 2x the MFMA work vs the 8-phase version.
//
// Region (slot,ks) = 64-B K-half: A 16 KB @ slot*32768+ks*16384, B same
// +65536. Row r, 16-B chunk c at slot c^((r>>1)&3) (consecutive-8-lane read
// quads cover all 8 bank groups -> conflict-free; staging realizes it by
// pre-swizzled GLOBAL source, LDS dest linear).
//
// Per-phase micro-pipeline (counted lgkm):
//   entry: issue kstep1 frags (6 ds_read)  [kstep0 frags issued mid-prev]
//   stage one region (4 global_load_lds)
//   gate lgkm(6) -> MFMA k0 (8) -> issue next phase's k0 frags (6)
//   gate lgkm(6) -> MFMA k1 (8) -> VM4 -> barrier
// Region rotation (iter i, tiles 2i=slot0 / 2i+1=slot1):
//   P0(s0,k0): stage s1k1<-T(2i+1).k1   P2(s1,k0): stage s0k1<-T(2i+2).k1
//   P1(s0,k1): stage s0k0<-T(2i+2).k0   P3(s1,k1): stage s1k0<-T(2i+3).k0
// Every region: staged at p, first read (mid p+2, consumed p+3); VM4 at each
// phase end enforces stage@q complete by end q+1 (<= mid p+2 reads). WAR:
// stage@p targets the region whose reads drained at p-1's gates, one barrier
// earlier. Prologue: stage s0k0,s0k1,s1k0 then VM4 (leaves s1k0 in flight).
// Peel (iter 15): P0 stages T31.k1 w/ VM4; P1 VM0; P2/P3 no VM.
// C/D 32x32: col=lane&31, row=(reg&3)+8*(reg>>2)+4*(lane>>5) [R2-validated].
// ============================================================================
__global__ __launch_bounds__(512, 2) void gemm_i8_k(const int8_t* __restrict__ A,
                                                    const int8_t* __restrict__ Bt,
                                                    float* __restrict__ C,
                                                    const float* __restrict__ w_scale,
                                                    const float* __restrict__ in_scale) {
    __shared__ int8_t lds[131072];

    const int tid  = threadIdx.x;
    const int lane = tid & 63;
    const int wave = tid >> 6;
    const int wr = wave >> 2;          // 0..1  (M half)
    const int wc = wave & 3;           // 0..3  (N quarter)
    const int lr = lane & 31;          // fragment row within 32-row tile
    const int h  = lane >> 5;          // 16-B chunk within 32-B kstep

    // Scales loaded+drained BEFORE the loop so no stray s_load pollutes the
    // counted lgkm gates; pinned live in a VGPR.
    const float fs = w_scale[0] * in_scale[0];
    asm volatile("s_waitcnt lgkmcnt(0)" ::: "memory");
    asm volatile("" :: "v"(fs));

    // XCD-aware swizzle: 512 wgs, 8 XCDs, each XCD gets an 8x8 tile chunk.
    const int bid = blockIdx.x;
    const int xcd = bid & 7;
    const int j   = bid >> 3;
    const int bm  = (xcd >> 1) * 8 + (j >> 3);   // 0..31
    const int bn  = (xcd & 1) * 8 + (j & 7);     // 0..15

    // Staging: row = tid>>2; LDS slot (tid&3) gets global chunk (tid&3)^((row>>1)&3).
    const int srow  = tid >> 2;
    const int sperm = ((tid & 3) ^ ((tid >> 3) & 3)) << 4;
    const int8_t* gA = A  + (size_t)(bm * 256 + srow) * KDIM + sperm;
    const int8_t* gB = Bt + (size_t)(bn * 256 + srow) * KDIM + sperm;
    const int ldsT = tid * 16;

#define RG(slot, ks) ((slot) * 32768 + (ks) * 16384)

#define STG4(slot, ks, kbyte)                                                              \
    lds_load16(gA + (kbyte) + (ks) * 64,          lds + RG(slot, ks) + ldsT);              \
    lds_load16(gA + (kbyte) + (ks) * 64 + 524288, lds + RG(slot, ks) + 8192 + ldsT);       \
    lds_load16(gB + (kbyte) + (ks) * 64,          lds + 65536 + RG(slot, ks) + ldsT);      \
    lds_load16(gB + (kbyte) + (ks) * 64 + 524288, lds + 65536 + RG(slot, ks) + 8192 + ldsT);

    // Fragment bases. row = wr*128 + mt*32 + lr -> (row>>1)&3 == (lr>>1)&3.
    // kstep j, half h -> global chunk 2j+h -> slot (2j+h)^sw; j=1 is ^32.
    const int sw  = ((h ^ ((lr >> 1) & 3)) << 4);
    const int aB0 = (wr * 128 + lr) * 64 + sw;
    const int aB1 = aB0 ^ 32;
    const int bB0 = 65536 + (wc * 64 + lr) * 64 + sw;
    const int bB1 = bB0 ^ 32;

    v16i acc[4][2] = {{}};
    v4i av0[2][4], bv0[2][2];   // kstep0 frags, double-buffered across phases
    v4i av1[4], bv1[2];         // kstep1 frags, within-phase

#define RD(off) (*(const v4i*)(lds + (off)))

#define IK0(buf, slot, ks)                                                                 \
    av0[buf][0] = RD(aB0 + RG(slot, ks) + 0 * 2048);                                       \
    av0[buf][1] = RD(aB0 + RG(slot, ks) + 1 * 2048);                                       \
    av0[buf][2] = RD(aB0 + RG(slot, ks) + 2 * 2048);                                       \
    av0[buf][3] = RD(aB0 + RG(slot, ks) + 3 * 2048);                                       \
    bv0[buf][0] = RD(bB0 + RG(slot, ks) + 0 * 2048);                                       \
    bv0[buf][1] = RD(bB0 + RG(slot, ks) + 1 * 2048);

#define IK1(slot, ks)                                                                      \
    av1[0] = RD(aB1 + RG(slot, ks) + 0 * 2048);                                            \
    av1[1] = RD(aB1 + RG(slot, ks) + 1 * 2048);                                            \
    av1[2] = RD(aB1 + RG(slot, ks) + 2 * 2048);                                            \
    av1[3] = RD(aB1 + RG(slot, ks) + 3 * 2048);                                            \
    bv1[0] = RD(bB1 + RG(slot, ks) + 0 * 2048);                                            \
    bv1[1] = RD(bB1 + RG(slot, ks) + 1 * 2048);

#define MFMA8(AARR, BARR)                                                                  \
    _Pragma("unroll")                                                                      \
    for (int mt = 0; mt < 4; ++mt)                                                         \
        _Pragma("unroll")                                                                  \
        for (int nt = 0; nt < 2; ++nt)                                                     \
            acc[mt][nt] = __builtin_amdgcn_mfma_i32_32x32x32_i8(                           \
                AARR[mt], BARR[nt], acc[mt][nt], 0, 0, 0);

#define VM4 asm volatile("s_waitcnt vmcnt(4)" ::: "memory");
#define VM0 asm volatile("s_waitcnt vmcnt(0)" ::: "memory");

// CB: k0 buffer for this phase. IK1S: kstep1 reads. STG: stage or empty.
// IKN: next phase's k0 reads or empty. G2: lgkm count after IKN (6 or 0).
#define PH(CB, IK1S, STG, IKN, G2, VMW)                                                    \
    {                                                                                      \
        IK1S                                                                               \
        STG                                                                                \
        asm volatile("s_waitcnt lgkmcnt(6)" ::: "memory");                                 \
        __builtin_amdgcn_sched_barrier(0);                                                 \
        __builtin_amdgcn_s_setprio(1);                                                     \
        MFMA8(av0[CB], bv0[CB])                                                            \
        __builtin_amdgcn_s_setprio(0);                                                     \
        __builtin_amdgcn_sched_barrier(0);                                                 \
        IKN                                                                                \
        asm volatile("s_waitcnt lgkmcnt(" #G2 ")" ::: "memory");                           \
        __builtin_amdgcn_sched_barrier(0);                                                 \
        __builtin_amdgcn_s_setprio(1);                                                     \
        MFMA8(av1, bv1)                                                                    \
        __builtin_amdgcn_s_setprio(0);                                                     \
        __builtin_amdgcn_sched_barrier(0);                                                 \
        VMW                                                                                \
        __builtin_amdgcn_s_barrier();                                                      \
        __builtin_amdgcn_sched_barrier(0);                                                 \
    }

    // Prologue: stage s0k0 (T0.k0), s0k1 (T0.k1), s1k0 (T1.k0) = 12 loads.
    STG4(0, 0, 0)
    STG4(0, 1, 0)
    STG4(1, 0, 128)
    VM4                                   // s0k0 + s0k1 landed; s1k0 in flight
    __builtin_amdgcn_s_barrier();
    __builtin_amdgcn_sched_barrier(0);
    IK0(0, 0, 0)                          // P0 kstep0 frags in flight

#pragma unroll 1
    for (int it = 0; it < 15; ++it) {
        const int kb = it * 256;
        PH(0, IK1(0, 0), STG4(1, 1, kb + 128), IK0(1, 0, 1), 6, VM4)
        PH(1, IK1(0, 1), STG4(0, 0, kb + 256), IK0(0, 1, 0), 6, VM4)
        PH(0, IK1(1, 0), STG4(0, 1, kb + 256), IK0(1, 1, 1), 6, VM4)
        PH(1, IK1(1, 1), STG4(1, 0, kb + 384), IK0(0, 0, 0), 6, VM4)
    }
    // Peel (tiles 30, 31): only T31.k1 still to stage.
    PH(0, IK1(0, 0), STG4(1, 1, 3968), IK0(1, 0, 1), 6, VM4)
    PH(1, IK1(0, 1), ,                 IK0(0, 1, 0), 6, VM0)
    PH(0, IK1(1, 0), ,                 IK0(1, 1, 1), 6, )
    PH(1, IK1(1, 1), ,                 ,             0, )

    // Epilogue: 32x32 D layout col = lane&31, row = (reg&3)+8*(reg>>2)+4*h.
    float* Cb = C + (size_t)(bm * 256 + wr * 128 + h * 4) * NDIM + bn * 256 + wc * 64 + lr;
#pragma unroll
    for (int mt = 0; mt < 4; ++mt)
#pragma unroll
        for (int nt = 0; nt < 2; ++nt)
#pragma unroll
            for (int r = 0; r < 16; ++r)
                Cb[(size_t)(mt * 32 + (r & 3) + 8 * (r >> 2)) * NDIM + nt * 32] =
                    (float)acc[mt][nt][r] * fs;

#undef RG
#undef STG4
#undef RD
#undef IK0
#undef IK1
#undef MFMA8
#undef PH
#undef VM4
#undef VM0
}

extern "C" void kernel_launch(void* const* d_in, const int* in_sizes, int n_in,
                              void* d_out, int out_size, void* d_ws, size_t ws_size,
                              hipStream_t stream) {
    const float* x        = (const float*)d_in[0];
    const int*   w        = (const int*)d_in[1];
    const float* w_scale  = (const float*)d_in[2];
    const float* in_scale = (const float*)d_in[3];
    float* out = (float*)d_out;

    int8_t* xq = (int8_t*)d_ws;                       // 33,554,432 B
    int8_t* wq = xq + (size_t)MDIM * KDIM;            // 16,777,216 B (48 MB total)

    prep_k<<<QBLOCKS + WBLOCKS, 256, 0, stream>>>(
        (const float4*)x, (int4*)xq, (const int4*)w, (int4*)wq, in_scale);

    dim3 grid(512);
    gemm_i8_k<<<grid, 512, 0, stream>>>(xq, wq, out, w_scale, in_scale);
}